// Round 3
// baseline (649.614 us; speedup 1.0000x reference)
//
#include <hip/hip_runtime.h>
#include <hip/hip_bf16.h>

// Problem dims (fixed by reference setup_inputs)
#define B_DIM 2048
#define D_DIM 512
#define C_DIM 32000
#define SCALE_F 32.0f
#define MARGIN_F 16.0f   // M * SCALE = 0.5 * 32

typedef unsigned short ushort_t;
typedef __bf16 bf16x8 __attribute__((ext_vector_type(8)));
typedef float floatx4 __attribute__((ext_vector_type(4)));
typedef unsigned short ushort4v __attribute__((ext_vector_type(4)));

// round-to-nearest-even fp32 -> bf16 (inputs are finite normals; no NaN path needed)
__device__ __forceinline__ unsigned short f2bf(float f) {
  union { float f; unsigned int u; } v; v.f = f;
  unsigned int u = v.u;
  u += 0x7FFFu + ((u >> 16) & 1u);
  return (unsigned short)(u >> 16);
}

// ---------------------------------------------------------------------------
// Pass 1: L2-normalize rows of x [2048,512] and weight [32000,512] (fp32),
// emit bf16 rows into workspace. One wave per row (512 elems = 8/lane).
// ---------------------------------------------------------------------------
__global__ __launch_bounds__(256) void normalize_kernel(
    const float* __restrict__ x, const float* __restrict__ w,
    ushort_t* __restrict__ xn, ushort_t* __restrict__ wn) {
  int gwave = (int)((blockIdx.x * 256 + threadIdx.x) >> 6);
  int lane = threadIdx.x & 63;
  const float* src;
  ushort_t* dst;
  if (gwave < B_DIM) {
    src = x + (size_t)gwave * D_DIM;
    dst = xn + (size_t)gwave * D_DIM;
  } else {
    int r = gwave - B_DIM;
    src = w + (size_t)r * D_DIM;
    dst = wn + (size_t)r * D_DIM;
  }
  const float4* s4 = (const float4*)src;
  float4 v0 = s4[lane];        // cols 4*lane   .. 4*lane+3
  float4 v1 = s4[64 + lane];   // cols 256+4*lane ..
  float s = v0.x * v0.x + v0.y * v0.y + v0.z * v0.z + v0.w * v0.w
          + v1.x * v1.x + v1.y * v1.y + v1.z * v1.z + v1.w * v1.w;
#pragma unroll
  for (int off = 32; off > 0; off >>= 1) s += __shfl_xor(s, off, 64);
  float inv = 1.0f / fmaxf(sqrtf(s), 1e-12f);
  ushort4v o0, o1;
  o0.x = f2bf(v0.x * inv); o0.y = f2bf(v0.y * inv);
  o0.z = f2bf(v0.z * inv); o0.w = f2bf(v0.w * inv);
  o1.x = f2bf(v1.x * inv); o1.y = f2bf(v1.y * inv);
  o1.z = f2bf(v1.z * inv); o1.w = f2bf(v1.w * inv);
  ((ushort4v*)dst)[lane] = o0;
  ((ushort4v*)dst)[64 + lane] = o1;
}

// ---------------------------------------------------------------------------
// Pass 2: C[2048,32000] = (Xn @ Wn^T) * 32 to both output halves; loss half
// gets -16 at (row, targets[row]) in the epilogue.
//
// STRUCTURE (T3 minimum-2-phase @ 256x256):
//   - BM=BN=256, BK=64, 512 thr = 8 waves (2M x 4N), per-wave 128x64 out.
//   - LDS: double-buffered A/B K-tiles = 2*(32K+32K) = 128 KiB (+1K tg).
//     1 block/CU; pipelining is intra-block (stage t+1 issued BEFORE
//     compute of t -> HBM/L2 latency hides under 64 MFMAs/wave), ONE
//     barrier per K-tile instead of two.
//   - K=512 -> 8 K-tiles; staged bytes halve vs 128-tile (512 MB total).
//   - LDS XOR-swizzle via pre-swizzled global source (linear gload_lds dest
//     + same-involution read): conflict-free ds_read_b128.
//   - nt stores for the 524 MB output stream; bijective XCD swizzle
//     (1000 blocks, q=125), bn-major: each XCD streams B once, A (2 MB)
//     L2-resident.
// ---------------------------------------------------------------------------
__device__ __forceinline__ void gload_lds16(const ushort_t* g, ushort_t* l) {
  __builtin_amdgcn_global_load_lds(
      (const __attribute__((address_space(1))) void*)g,
      (__attribute__((address_space(3))) void*)l, 16, 0, 0);
}

__global__ __launch_bounds__(512, 2) void gemm_margin_kernel(
    const ushort_t* __restrict__ A,    // [2048][512]  normalized bf16
    const ushort_t* __restrict__ Bw,   // [32000][512] normalized bf16
    const int* __restrict__ targets,   // [2048]
    float* __restrict__ out_loss, float* __restrict__ out_pred) {
  __shared__ __align__(16) ushort_t As[2 * 256 * 64];  // 64 KiB, [d][row][chunk^row&7]
  __shared__ __align__(16) ushort_t Bs[2 * 256 * 64];  // 64 KiB
  __shared__ int tg[256];

  int tid = threadIdx.x;
  int wave = tid >> 6;
  int lane = tid & 63;

  // Bijective XCD swizzle: 1000 blocks, 1000 % 8 == 0, q = 125.
  // work = bn*8 + bm -> the 8 blocks sharing a B-tile are consecutive works,
  // i.e. same XCD: B fetched ~once per XCD, A fully L2-resident.
  int bid = (int)blockIdx.x;
  int work = (bid & 7) * 125 + (bid >> 3);
  int bm = work & 7;    // 8 M-blocks
  int bn = work >> 3;   // 125 N-blocks

  if (tid < 256) tg[tid] = targets[bm * 256 + tid];

  int wr = wave >> 2;   // 0..1 : M half (128 rows)
  int wc = wave & 3;    // 0..3 : N quarter (64 cols)

  // Staging: one issue = 512 thr x 16 B = 8 KB = 64 rows x 128 B.
  // Pre-swizzled source: LDS slot (row, c) holds G(row, c ^ (row&7)).
  int srow = tid >> 3;                  // 0..63 within an issue
  int schunk = (tid & 7) ^ (srow & 7);  // 16B chunk index in global row
  const ushort_t* gA = A + (size_t)(bm * 256 + srow) * D_DIM + schunk * 8;
  const ushort_t* gB = Bw + (size_t)(bn * 256 + srow) * D_DIM + schunk * 8;

  // LDS wave-uniform bases (gload_lds writes base + lane*16B, linear).
  // ushort offsets: dbuf d -> d*16384, issue q -> q*4096, wave -> wave*512.
  ushort_t* lA = As + wave * 512;
  ushort_t* lB = Bs + wave * 512;

  floatx4 acc[8][4];
#pragma unroll
  for (int i = 0; i < 8; i++)
#pragma unroll
    for (int j = 0; j < 4; j++) acc[i][j] = {0.0f, 0.0f, 0.0f, 0.0f};

  int fm = lane & 15;   // M/N index within a 16-tile
  int q4 = lane >> 4;   // K quad (8 elems)

#define STAGE(d, t)                                                          \
  do {                                                                       \
    _Pragma("unroll")                                                        \
    for (int q = 0; q < 4; q++) {                                            \
      gload_lds16(gA + (size_t)(t) * 64 + (size_t)q * 64 * D_DIM,            \
                  lA + (d) * 16384 + q * 4096);                              \
      gload_lds16(gB + (size_t)(t) * 64 + (size_t)q * 64 * D_DIM,            \
                  lB + (d) * 16384 + q * 4096);                              \
    }                                                                        \
  } while (0)

#define COMPUTE(d)                                                           \
  do {                                                                       \
    _Pragma("unroll")                                                        \
    for (int kk = 0; kk < 2; kk++) {                                         \
      int ch = (kk * 4 + q4) ^ (fm & 7); /* read-side swizzle; row&7==fm&7 */\
      bf16x8 bfr[4];                                                         \
      _Pragma("unroll")                                                      \
      for (int j = 0; j < 4; j++)                                            \
        bfr[j] = *(const bf16x8*)(Bs + (d) * 16384 +                         \
                                  (wc * 64 + j * 16 + fm) * 64 + ch * 8);    \
      _Pragma("unroll")                                                      \
      for (int i = 0; i < 8; i++) {                                          \
        bf16x8 af = *(const bf16x8*)(As + (d) * 16384 +                      \
                                     (wr * 128 + i * 16 + fm) * 64 + ch * 8);\
        _Pragma("unroll")                                                    \
        for (int j = 0; j < 4; j++)                                          \
          acc[i][j] = __builtin_amdgcn_mfma_f32_16x16x32_bf16(               \
              af, bfr[j], acc[i][j], 0, 0, 0);                               \
      }                                                                      \
    }                                                                        \
  } while (0)

  // Prologue: stage K-tile 0, drain once.
  STAGE(0, 0);
  __syncthreads();  // also covers tg[] writes

  // 2-phase main loop: issue next tile's loads, THEN compute current tile.
  // The single __syncthreads (vmcnt(0)+lgkmcnt(0)+barrier) lands after a
  // full compute phase has hidden the load latency.
#pragma unroll
  for (int t = 0; t < 7; t++) {
    int cur = t & 1;
    STAGE(cur ^ 1, t + 1);
    COMPUTE(cur);
    __syncthreads();
  }
  COMPUTE(1);  // tile 7 sits in dbuf 1

  // Epilogue. C/D layout (16x16x32): col = lane&15, row = (lane>>4)*4 + reg.
  // Nontemporal: 524 MB pure stream must not thrash L2.
  int gn0 = bn * 256 + wc * 64;
  int r4 = lane >> 4;
#pragma unroll
  for (int i = 0; i < 8; i++) {
#pragma unroll
    for (int r = 0; r < 4; r++) {
      int lm = wr * 128 + i * 16 + r4 * 4 + r;  // row within 256-block
      int gm = bm * 256 + lm;
      int tgt = tg[lm];
      size_t rowoff = (size_t)gm * C_DIM;
#pragma unroll
      for (int j = 0; j < 4; j++) {
        int gn = gn0 + j * 16 + fm;
        float v = acc[i][j][r] * SCALE_F;
        __builtin_nontemporal_store(v, &out_pred[rowoff + gn]);
        __builtin_nontemporal_store((gn == tgt) ? (v - MARGIN_F) : v,
                                    &out_loss[rowoff + gn]);
      }
    }
  }
#undef STAGE
#undef COMPUTE
}

extern "C" void kernel_launch(void* const* d_in, const int* in_sizes, int n_in,
                              void* d_out, int out_size, void* d_ws, size_t ws_size,
                              hipStream_t stream) {
  const float* x = (const float*)d_in[0];
  const float* w = (const float*)d_in[1];
  const int* targets = (const int*)d_in[2];

  float* out_loss = (float*)d_out;                       // first tuple element
  float* out_pred = out_loss + (size_t)B_DIM * C_DIM;    // second tuple element

  ushort_t* xn = (ushort_t*)d_ws;                        // 2048*512 bf16 = 2 MB
  ushort_t* wn = xn + (size_t)B_DIM * D_DIM;             // 32000*512 bf16 = 32.75 MB

  // 2048 + 32000 = 34048 rows, one wave each, 4 waves/block
  normalize_kernel<<<(B_DIM + C_DIM) / 4, 256, 0, stream>>>(x, w, xn, wn);

  // 8 x 125 = 1000 blocks, 512 threads (8 waves)
  gemm_margin_kernel<<<(B_DIM / 256) * (C_DIM / 256), 512, 0, stream>>>(
      xn, wn, targets, out_loss, out_pred);
}

// Round 5
// 602.285 us; speedup vs baseline: 1.0786x; 1.0786x over previous
//
#include <hip/hip_runtime.h>
#include <hip/hip_bf16.h>

// Problem dims (fixed by reference setup_inputs)
#define B_DIM 2048
#define D_DIM 512
#define C_DIM 32000
#define SCALE_F 32.0f
#define MARGIN_F 16.0f   // M * SCALE = 0.5 * 32

typedef unsigned short ushort_t;
typedef __bf16 bf16x8 __attribute__((ext_vector_type(8)));
typedef float floatx4 __attribute__((ext_vector_type(4)));
typedef unsigned short ushort4v __attribute__((ext_vector_type(4)));

// round-to-nearest-even fp32 -> bf16 (inputs are finite normals; no NaN path needed)
__device__ __forceinline__ unsigned short f2bf(float f) {
  union { float f; unsigned int u; } v; v.f = f;
  unsigned int u = v.u;
  u += 0x7FFFu + ((u >> 16) & 1u);
  return (unsigned short)(u >> 16);
}

// ---------------------------------------------------------------------------
// Pass 1: L2-normalize rows of x [2048,512] and weight [32000,512] (fp32),
// emit bf16 rows into workspace. One wave per row (512 elems = 8/lane).
// ---------------------------------------------------------------------------
__global__ __launch_bounds__(256) void normalize_kernel(
    const float* __restrict__ x, const float* __restrict__ w,
    ushort_t* __restrict__ xn, ushort_t* __restrict__ wn) {
  int gwave = (int)((blockIdx.x * 256 + threadIdx.x) >> 6);
  int lane = threadIdx.x & 63;
  const float* src;
  ushort_t* dst;
  if (gwave < B_DIM) {
    src = x + (size_t)gwave * D_DIM;
    dst = xn + (size_t)gwave * D_DIM;
  } else {
    int r = gwave - B_DIM;
    src = w + (size_t)r * D_DIM;
    dst = wn + (size_t)r * D_DIM;
  }
  const float4* s4 = (const float4*)src;
  float4 v0 = s4[lane];        // cols 4*lane   .. 4*lane+3
  float4 v1 = s4[64 + lane];   // cols 256+4*lane ..
  float s = v0.x * v0.x + v0.y * v0.y + v0.z * v0.z + v0.w * v0.w
          + v1.x * v1.x + v1.y * v1.y + v1.z * v1.z + v1.w * v1.w;
#pragma unroll
  for (int off = 32; off > 0; off >>= 1) s += __shfl_xor(s, off, 64);
  float inv = 1.0f / fmaxf(sqrtf(s), 1e-12f);
  ushort4v o0, o1;
  o0.x = f2bf(v0.x * inv); o0.y = f2bf(v0.y * inv);
  o0.z = f2bf(v0.z * inv); o0.w = f2bf(v0.w * inv);
  o1.x = f2bf(v1.x * inv); o1.y = f2bf(v1.y * inv);
  o1.z = f2bf(v1.z * inv); o1.w = f2bf(v1.w * inv);
  ((ushort4v*)dst)[lane] = o0;
  ((ushort4v*)dst)[64 + lane] = o1;
}

// ---------------------------------------------------------------------------
// Pass 2: C[2048,32000] = (Xn @ Wn^T) * 32 to both output halves; loss half
// gets -16 at (row, targets[row]) in the epilogue.
//
// Structure = round-1 measured-best (128x128 tile, BK=64, 4 waves, swizzled
// global_load_lds staging, ~4 blocks/CU for natural cross-block overlap of
// epilogue writes with other blocks' k-loops).
//
// LDS-TRANSPOSED EPILOGUE (theory: kernel is epilogue-write-bound).
// Old epilogue stored 4 B/lane at col=j*16+fm -> 64 B segments per quarter-
// wave; 524 MB of nt 64B-segment stores ~ 2 TB/s ~ 260 us (= the observed
// GEMM residual; explains why all k-loop opts were neutral).
// Now: per i, each wave scatter-writes its 16x64 fp32 sub-tile (scaled) to a
// private 4 KB LDS region (conflict-free: each 16-lane quarter writes 16
// consecutive floats of one row), lgkmcnt(0), reads back floatx4/lane with
// lanes 0..15 covering one row's 64 cols -> nt stores of 256B-contiguous
// segments (1 KB/inst). LDS round-trip for 524 MB ~ 15 us. Same arithmetic
// order ((acc*32)-16) -> bit-identical output.
// NOTE: nt stores must use clang ext_vector (floatx4) — HIP's float4 class
// is rejected by __builtin_nontemporal_store (round-4 compile error).
// ---------------------------------------------------------------------------
__device__ __forceinline__ void gload_lds16(const ushort_t* g, ushort_t* l) {
  __builtin_amdgcn_global_load_lds(
      (const __attribute__((address_space(1))) void*)g,
      (__attribute__((address_space(3))) void*)l, 16, 0, 0);
}

__global__ __launch_bounds__(256) void gemm_margin_kernel(
    const ushort_t* __restrict__ A,    // [2048][512]  normalized bf16
    const ushort_t* __restrict__ Bw,   // [32000][512] normalized bf16
    const int* __restrict__ targets,   // [2048]
    float* __restrict__ out_loss, float* __restrict__ out_pred) {
  __shared__ __align__(16) ushort_t As[128 * 64];   // 16 KB, [row][chunk^(row&7)]
  __shared__ __align__(16) ushort_t Bs[128 * 64];   // 16 KB
  __shared__ int tg[128];

  int tid = threadIdx.x;
  int wave = tid >> 6;
  int lane = tid & 63;

  // Bijective XCD swizzle: 4000 blocks, 4000 % 8 == 0, q = 500.
  // work = bn*16 + bm -> the 16 blocks sharing a B-tile are consecutive
  // works, i.e. same XCD: B streamed ~once per XCD, A (2 MB) L2-resident.
  int bid = (int)blockIdx.x;
  int work = (bid & 7) * 500 + (bid >> 3);
  int bm = work & 15;   // 16 M-blocks
  int bn = work >> 4;   // 250 N-blocks

  if (tid < 128) tg[tid] = targets[bm * 128 + tid];

  int wm = wave & 1;   // 2x2 wave grid over the 128x128 tile
  int wn = wave >> 1;

  // Staging: one issue = 256 thr x 16 B = 32 rows x 128 B.
  // Pre-swizzled source: LDS slot (row, c) holds G(row, c ^ (row&7)).
  int srow = tid >> 3;                  // 0..31 within an issue
  int schunk = (tid & 7) ^ (srow & 7);  // 16B chunk index in global row
  const ushort_t* gA = A + (size_t)(bm * 128 + srow) * D_DIM + schunk * 8;
  const ushort_t* gB = Bw + (size_t)(bn * 128 + srow) * D_DIM + schunk * 8;

  // LDS wave-uniform bases (gload_lds writes base + lane*16B, linear);
  // issue q covers rows q*32..q*32+31.
  ushort_t* lA = As + wave * 512;
  ushort_t* lB = Bs + wave * 512;

  floatx4 acc[4][4];
#pragma unroll
  for (int i = 0; i < 4; i++)
#pragma unroll
    for (int j = 0; j < 4; j++) acc[i][j] = {0.0f, 0.0f, 0.0f, 0.0f};

  int fm = lane & 15;   // M/N index within a 16-tile
  int q4 = lane >> 4;   // K quad (8 elems)

  for (int k0 = 0; k0 < D_DIM; k0 += 64) {
    __syncthreads();  // previous iter's LDS reads done before overwrite
#pragma unroll
    for (int q = 0; q < 4; q++) {
      gload_lds16(gA + (size_t)q * 32 * D_DIM, lA + q * 2048);
      gload_lds16(gB + (size_t)q * 32 * D_DIM, lB + q * 2048);
    }
    gA += 64;
    gB += 64;
    __syncthreads();  // compiler drains vmcnt(0) before s_barrier

#pragma unroll
    for (int kk = 0; kk < 2; kk++) {
      int ch = (kk * 4 + q4) ^ (fm & 7);  // read-side swizzle; row&7 == fm&7
      bf16x8 bfr[4];
#pragma unroll
      for (int j = 0; j < 4; j++)
        bfr[j] = *(const bf16x8*)(Bs + (wn * 64 + j * 16 + fm) * 64 + ch * 8);
#pragma unroll
      for (int i = 0; i < 4; i++) {
        bf16x8 af = *(const bf16x8*)(As + (wm * 64 + i * 16 + fm) * 64 + ch * 8);
#pragma unroll
        for (int j = 0; j < 4; j++)
          acc[i][j] = __builtin_amdgcn_mfma_f32_16x16x32_bf16(af, bfr[j], acc[i][j], 0, 0, 0);
      }
    }
  }

  // ---------------- LDS-transposed epilogue ----------------
  __syncthreads();  // all waves done reading As/Bs; safe to repurpose As

  // Per-wave private 4 KB region: [16 rows][64 cols] fp32, stride 64.
  float* eps = (float*)As + wave * 1024;
  int c4 = lane & 15;   // column chunk (4 floats)
  int rq = lane >> 4;   // row quarter
  int gn0 = bn * 128 + wn * 64;

#pragma unroll
  for (int i = 0; i < 4; i++) {
    // Scatter-write 16x64 sub-tile (scaled). Quarter rq writes row rq*4+r,
    // cols j*16+fm: 16 consecutive floats -> conflict-free.
#pragma unroll
    for (int j = 0; j < 4; j++)
#pragma unroll
      for (int r = 0; r < 4; r++)
        eps[(rq * 4 + r) * 64 + j * 16 + fm] = acc[i][j][r] * SCALE_F;

    // Wave-internal cross-lane handoff: drain LDS writes before reads.
    asm volatile("s_waitcnt lgkmcnt(0)" ::: "memory");

    // Read back: lanes 0..15 = one row's 64 cols (256B contiguous / quarter).
#pragma unroll
    for (int s = 0; s < 4; s++) {
      int rowL = s * 4 + rq;
      floatx4 v = *(const floatx4*)(eps + rowL * 64 + c4 * 4);
      int lm = wm * 64 + i * 16 + rowL;   // row within 128-block
      int gm = bm * 128 + lm;
      int tgt = tg[lm];
      int gnb = gn0 + c4 * 4;
      size_t off = (size_t)gm * C_DIM + gnb;
      __builtin_nontemporal_store(v, (floatx4*)(out_pred + off));
      floatx4 l = v;
      l.x -= (gnb + 0 == tgt) ? MARGIN_F : 0.0f;
      l.y -= (gnb + 1 == tgt) ? MARGIN_F : 0.0f;
      l.z -= (gnb + 2 == tgt) ? MARGIN_F : 0.0f;
      l.w -= (gnb + 3 == tgt) ? MARGIN_F : 0.0f;
      __builtin_nontemporal_store(l, (floatx4*)(out_loss + off));
    }
    // WAR fence: next i's LDS writes must not be hoisted above these reads
    // (HW LDS is in-order per wave; this blocks compiler reordering).
    asm volatile("" ::: "memory");
  }
}

extern "C" void kernel_launch(void* const* d_in, const int* in_sizes, int n_in,
                              void* d_out, int out_size, void* d_ws, size_t ws_size,
                              hipStream_t stream) {
  const float* x = (const float*)d_in[0];
  const float* w = (const float*)d_in[1];
  const int* targets = (const int*)d_in[2];

  float* out_loss = (float*)d_out;                       // first tuple element
  float* out_pred = out_loss + (size_t)B_DIM * C_DIM;    // second tuple element

  ushort_t* xn = (ushort_t*)d_ws;                        // 2048*512 bf16 = 2 MB
  ushort_t* wn = xn + (size_t)B_DIM * D_DIM;             // 32000*512 bf16 = 32.75 MB

  // 2048 + 32000 = 34048 rows, one wave each, 4 waves/block
  normalize_kernel<<<(B_DIM + C_DIM) / 4, 256, 0, stream>>>(x, w, xn, wn);

  // 16 x 250 = 4000 blocks
  gemm_margin_kernel<<<(B_DIM / 128) * (C_DIM / 128), 256, 0, stream>>>(
      xn, wn, targets, out_loss, out_pred);
}